// Round 11
// baseline (401.711 us; speedup 1.0000x reference)
//
#include <hip/hip_runtime.h>
#include <hip/hip_bf16.h>
#include <stdint.h>

typedef __attribute__((ext_vector_type(4))) float f32x4;
typedef __attribute__((ext_vector_type(2))) float f32x2;
typedef __attribute__((ext_vector_type(8))) short short8;
typedef __attribute__((ext_vector_type(4))) unsigned int u32x4;

__device__ __forceinline__ unsigned short f2bf(float x) {
  __hip_bfloat16 h = __float2bfloat16(x);
  union { __hip_bfloat16 b; unsigned short s; } u; u.b = h;
  return u.s;
}
__device__ __forceinline__ unsigned int pkbf(float lo, float hi) {
  return (unsigned int)f2bf(lo) | ((unsigned int)f2bf(hi) << 16);
}
__device__ __forceinline__ f32x4 ld4(const float* p) { return *(const f32x4*)p; }

// R11 PROBE: identical R8 structure, but the body executes 3 full passes
// (re-zero acc, recompute, re-store same values). Purpose: push the kernel
// dispatch above the 78us fillBuffer cutoff so rocprof's top-5 finally shows
// OUR counters (FETCH/VALUBusy/MfmaUtil/occupancy), and measure warm-pass
// time via dur_us delta. Store stays inside the pass loop so no pass is DCE'd.

#define MSK(v, k) (((k) == arow) ? 0.f : (v))

#define LOADA(kt, Aq) do {                                               \
    const float* p_ = aP + (kt) * 64;                                    \
    Aq[0] = ld4(p_); Aq[1] = ld4(p_ + 4);                                \
    Aq[2] = ld4(p_ + 32); Aq[3] = ld4(p_ + 36);                          \
  } while (0)

#define STAGE_LOAD(q1, h, S_) do {                                       \
    const float* p_ = bP0 + (q1) * 16384 + (h) * 4096;                   \
    _Pragma("unroll") for (int e_ = 0; e_ < 8; ++e_)                     \
      S_[e_] = *(const f32x2*)(p_ + e_ * 128);                           \
  } while (0)

#define STAGE_WRITE(nb, h, S_) do {                                      \
    u32x4 ua_, ub_;                                                      \
    ua_[0] = pkbf(S_[0].x, S_[1].x); ua_[1] = pkbf(S_[2].x, S_[3].x);    \
    ua_[2] = pkbf(S_[4].x, S_[5].x); ua_[3] = pkbf(S_[6].x, S_[7].x);    \
    ub_[0] = pkbf(S_[0].y, S_[1].y); ub_[1] = pkbf(S_[2].y, S_[3].y);    \
    ub_[2] = pkbf(S_[4].y, S_[5].y); ub_[3] = pkbf(S_[6].y, S_[7].y);    \
    char* p_ = wB + (nb) * 32768 + (h) * 1024;                           \
    *(u32x4*)p_ = ua_; *(u32x4*)(p_ + 16) = ub_;                         \
  } while (0)

#define COMPUTE(buf, kt, Aq) do {                                        \
    short8 af0_, af1_;                                                   \
    {                                                                    \
      union { u32x4 q; short8 s; } u0_, u1_;                             \
      if ((kt) == diag_kt) {                                             \
        const int jb_ = (kt) * 64 + kg;                                  \
        u0_.q[0] = pkbf(MSK(Aq[0][0], jb_ + 0),  MSK(Aq[0][1], jb_ + 1)); \
        u0_.q[1] = pkbf(MSK(Aq[0][2], jb_ + 2),  MSK(Aq[0][3], jb_ + 3)); \
        u0_.q[2] = pkbf(MSK(Aq[1][0], jb_ + 4),  MSK(Aq[1][1], jb_ + 5)); \
        u0_.q[3] = pkbf(MSK(Aq[1][2], jb_ + 6),  MSK(Aq[1][3], jb_ + 7)); \
        u1_.q[0] = pkbf(MSK(Aq[2][0], jb_ + 32), MSK(Aq[2][1], jb_ + 33)); \
        u1_.q[1] = pkbf(MSK(Aq[2][2], jb_ + 34), MSK(Aq[2][3], jb_ + 35)); \
        u1_.q[2] = pkbf(MSK(Aq[3][0], jb_ + 36), MSK(Aq[3][1], jb_ + 37)); \
        u1_.q[3] = pkbf(MSK(Aq[3][2], jb_ + 38), MSK(Aq[3][3], jb_ + 39)); \
      } else {                                                           \
        u0_.q[0] = pkbf(Aq[0][0], Aq[0][1]); u0_.q[1] = pkbf(Aq[0][2], Aq[0][3]); \
        u0_.q[2] = pkbf(Aq[1][0], Aq[1][1]); u0_.q[3] = pkbf(Aq[1][2], Aq[1][3]); \
        u1_.q[0] = pkbf(Aq[2][0], Aq[2][1]); u1_.q[1] = pkbf(Aq[2][2], Aq[2][3]); \
        u1_.q[2] = pkbf(Aq[3][0], Aq[3][1]); u1_.q[3] = pkbf(Aq[3][2], Aq[3][3]); \
      }                                                                  \
      af0_ = u0_.s; af1_ = u1_.s;                                        \
    }                                                                    \
    const char* base_ = rP + (buf) * 32768;                              \
    const int c_ = (kt) & 1;                                             \
    _Pragma("unroll")                                                    \
    for (int n_ = 0; n_ < 8; ++n_) {                                     \
      short8 bf0_ = *(const short8*)(base_ + (n_ * 4 + 2 * c_ + 0) * 1024); \
      acc[n_] = __builtin_amdgcn_mfma_f32_16x16x32_bf16(af0_, bf0_, acc[n_], 0, 0, 0); \
      short8 bf1_ = *(const short8*)(base_ + (n_ * 4 + 2 * c_ + 1) * 1024); \
      acc[n_] = __builtin_amdgcn_mfma_f32_16x16x32_bf16(af1_, bf1_, acc[n_], 0, 0, 0); \
    }                                                                    \
  } while (0)

__global__ __launch_bounds__(256, 2) void gcn_kernel(
    const float* __restrict__ means, const float* __restrict__ adj,
    float* __restrict__ out) {
  __shared__ char ldsB[65536];  // 2 x 32 KB B-phase buffers

  const int tid = (int)threadIdx.x;
  const int l = tid & 63;
  const int w = tid >> 6;  // wave 0..3
  const int bid = (int)blockIdx.x;
  const int batch = (bid & 7) * 4 + (bid >> 7);
  const int rtile = (bid >> 3) & 15;
  const int rbase = rtile * 64;

  const float* aB = adj + (size_t)batch * 1048576;
  const float* mB = means + (size_t)batch * 131072;
  float* oB = out + (size_t)batch * 131072;

  const int arow = rbase + w * 16 + (l & 15);
  const int kg = (l >> 4) * 8;
  const float* aP = aB + (size_t)arow * 1024 + kg;
  const int diag_kt = arow >> 6;  // wave-uniform

  const int n_t = tid >> 5;
  const int g_t = (tid >> 3) & 3;
  const int fc_t = (tid & 7) * 2;
  const float* bP0 = mB + (size_t)(g_t * 8) * 128 + n_t * 16 + fc_t;
  char* wB = ldsB + n_t * 4096 + g_t * 256 + fc_t * 16;
  const char* rP = ldsB + l * 16;

  const int orow = rbase + w * 16 + (l >> 4) * 4;
  const int ocol = l & 15;
  float* op = oB + (size_t)orow * 128 + ocol;

#pragma unroll 1
  for (int pass = 0; pass < 3; ++pass) {
    f32x4 acc[8];
#pragma unroll
    for (int n = 0; n < 8; ++n) { f32x4 z = {0.f, 0.f, 0.f, 0.f}; acc[n] = z; }

    f32x4 Ar[2][4];

    __syncthreads();  // protect LDS buf0 from previous pass (defensive)
    {
      f32x2 S0[8], S1[8], S2[8], S3[8];
      STAGE_LOAD(0, 0, S0); STAGE_LOAD(0, 1, S1);
      STAGE_LOAD(0, 2, S2); STAGE_LOAD(0, 3, S3);
      LOADA(0, Ar[0]);
      STAGE_WRITE(0, 0, S0); STAGE_WRITE(0, 1, S1);
      STAGE_WRITE(0, 2, S2); STAGE_WRITE(0, 3, S3);
    }
    __syncthreads();

#pragma unroll
    for (int kt = 0; kt < 16; ++kt) {
      const int q = kt >> 1;
      const int c = kt & 1;
      const int buf = q & 1;
      const int nbuf = buf ^ 1;
      const int cur = kt & 1;
      const int nxt = cur ^ 1;

      if (kt < 15) LOADA(kt + 1, Ar[nxt]);

      f32x2 S0[8], S1[8];
      if (q < 7) {
        STAGE_LOAD(q + 1, 2 * c + 0, S0);
        STAGE_LOAD(q + 1, 2 * c + 1, S1);
      }

      COMPUTE(buf, kt, Ar[cur]);

      if (q < 7) {
        STAGE_WRITE(nbuf, 2 * c + 0, S0);
        STAGE_WRITE(nbuf, 2 * c + 1, S1);
      }
      if (c == 1) __syncthreads();
    }

    // Store inside the pass loop (keeps every pass live; idempotent values).
#pragma unroll
    for (int n = 0; n < 8; ++n)
#pragma unroll
      for (int j = 0; j < 4; ++j)
        op[j * 128 + n * 16] = acc[n][j];
  }
}

extern "C" void kernel_launch(void* const* d_in, const int* in_sizes, int n_in,
                              void* d_out, int out_size, void* d_ws, size_t ws_size,
                              hipStream_t stream) {
  const float* means = (const float*)d_in[0];  // regional_means (32,1024,128)
  const float* adj = (const float*)d_in[1];    // adj (32,1024,1024)
  float* out = (float*)d_out;                  // (32,1024,128) f32
  hipLaunchKernelGGL(gcn_kernel, dim3(512), dim3(256), 0, stream, means, adj, out);
}

// Round 12
// 219.661 us; speedup vs baseline: 1.8288x; 1.8288x over previous
//
#include <hip/hip_runtime.h>
#include <hip/hip_bf16.h>
#include <stdint.h>

typedef __attribute__((ext_vector_type(4))) float f32x4;
typedef __attribute__((ext_vector_type(8))) short short8;
typedef __attribute__((ext_vector_type(4))) unsigned int u32x4;

__device__ __forceinline__ unsigned short f2bf(float x) {
  __hip_bfloat16 h = __float2bfloat16(x);
  union { __hip_bfloat16 b; unsigned short s; } u; u.b = h;
  return u.s;
}
__device__ __forceinline__ unsigned int pkbf(float lo, float hi) {
  return (unsigned int)f2bf(lo) | ((unsigned int)f2bf(hi) << 16);
}
__device__ __forceinline__ f32x4 ld4(const float* p) { return *(const f32x4*)p; }

// R12: request-byte reduction.
// Probe (R11) showed the kernel is VMEM-request-throughput-bound: 470 MB
// requested/pass at 5.2 TB/s ~= 83% of the m13 streaming ceiling; warm (L3)
// passes no faster than cold. So: (1) pre-convert means f32->bf16 into d_ws,
// already in MFMA fragment order -> B requests halve and load via
// global_load_lds (16B/lane, no VGPR round trip, no per-WG convert);
// (2) 128-row tiles (grid 256x512thr) -> B redundancy 16x->8x.
// Requested bytes: 470 -> ~208 MB (A 128 f32 + B 64 bf16 + C 16).
//
// ws chunk layout (16B units): chunk[b*16384 + q*2048 + idx16] where
// idx16 = (n*4+s)*64 + ksub*16 + lc holds bf16 means[b][k0+e][n*16+lc],
// k0 = (q*16+s*4+ksub)*8, e=0..7. This equals the LDS fragment-major order,
// so glds (linear dest = base + lane*16) lands fragments exactly in place.

__global__ __launch_bounds__(256) void conv_means(
    const float* __restrict__ means, u32x4* __restrict__ wsB) {
  const int flat = (int)blockIdx.x * 256 + (int)threadIdx.x;  // 0..524287
  const int b = flat >> 14;
  const int rem = flat & 16383;
  const int q = rem >> 11;
  const int idx16 = rem & 2047;
  const int n = idx16 >> 8;
  const int s = (idx16 >> 6) & 3;
  const int ksub = (idx16 >> 4) & 3;
  const int lc = idx16 & 15;
  const int c = n * 16 + lc;
  const int k0 = (q * 16 + s * 4 + ksub) * 8;
  const float* src = means + ((size_t)b * 1024 + k0) * 128 + c;
  u32x4 v;
  v[0] = pkbf(src[0 * 128], src[1 * 128]);
  v[1] = pkbf(src[2 * 128], src[3 * 128]);
  v[2] = pkbf(src[4 * 128], src[5 * 128]);
  v[3] = pkbf(src[6 * 128], src[7 * 128]);
  wsB[flat] = v;
}

#define MSK(v, k) (((k) == arow) ? 0.f : (v))

#define LOADA(kt, Aq) do {                                               \
    const float* p_ = aP + (kt) * 64;                                    \
    Aq[0] = ld4(p_); Aq[1] = ld4(p_ + 4);                                \
    Aq[2] = ld4(p_ + 32); Aq[3] = ld4(p_ + 36);                          \
  } while (0)

#define COMPUTE(buf, kt, Aq) do {                                        \
    short8 af0_, af1_;                                                   \
    {                                                                    \
      union { u32x4 q; short8 s; } u0_, u1_;                             \
      if ((kt) == diag_kt) {                                             \
        const int jb_ = (kt) * 64 + kg;                                  \
        u0_.q[0] = pkbf(MSK(Aq[0][0], jb_ + 0),  MSK(Aq[0][1], jb_ + 1)); \
        u0_.q[1] = pkbf(MSK(Aq[0][2], jb_ + 2),  MSK(Aq[0][3], jb_ + 3)); \
        u0_.q[2] = pkbf(MSK(Aq[1][0], jb_ + 4),  MSK(Aq[1][1], jb_ + 5)); \
        u0_.q[3] = pkbf(MSK(Aq[1][2], jb_ + 6),  MSK(Aq[1][3], jb_ + 7)); \
        u1_.q[0] = pkbf(MSK(Aq[2][0], jb_ + 32), MSK(Aq[2][1], jb_ + 33)); \
        u1_.q[1] = pkbf(MSK(Aq[2][2], jb_ + 34), MSK(Aq[2][3], jb_ + 35)); \
        u1_.q[2] = pkbf(MSK(Aq[3][0], jb_ + 36), MSK(Aq[3][1], jb_ + 37)); \
        u1_.q[3] = pkbf(MSK(Aq[3][2], jb_ + 38), MSK(Aq[3][3], jb_ + 39)); \
      } else {                                                           \
        u0_.q[0] = pkbf(Aq[0][0], Aq[0][1]); u0_.q[1] = pkbf(Aq[0][2], Aq[0][3]); \
        u0_.q[2] = pkbf(Aq[1][0], Aq[1][1]); u0_.q[3] = pkbf(Aq[1][2], Aq[1][3]); \
        u1_.q[0] = pkbf(Aq[2][0], Aq[2][1]); u1_.q[1] = pkbf(Aq[2][2], Aq[2][3]); \
        u1_.q[2] = pkbf(Aq[3][0], Aq[3][1]); u1_.q[3] = pkbf(Aq[3][2], Aq[3][3]); \
      }                                                                  \
      af0_ = u0_.s; af1_ = u1_.s;                                        \
    }                                                                    \
    const char* base_ = rP + (buf) * 32768;                              \
    const int c_ = (kt) & 1;                                             \
    _Pragma("unroll")                                                    \
    for (int n_ = 0; n_ < 8; ++n_) {                                     \
      short8 bf0_ = *(const short8*)(base_ + (n_ * 4 + 2 * c_ + 0) * 1024); \
      acc[n_] = __builtin_amdgcn_mfma_f32_16x16x32_bf16(af0_, bf0_, acc[n_], 0, 0, 0); \
      short8 bf1_ = *(const short8*)(base_ + (n_ * 4 + 2 * c_ + 1) * 1024); \
      acc[n_] = __builtin_amdgcn_mfma_f32_16x16x32_bf16(af1_, bf1_, acc[n_], 0, 0, 0); \
    }                                                                    \
  } while (0)

// Stage 4x glds calls for phase q1 into LDS buffer nb (wave-uniform dest base).
#define GLDSPHASE(nb, q1) do {                                           \
    _Pragma("unroll")                                                    \
    for (int call_ = 0; call_ < 4; ++call_) {                            \
      const u32x4* g_ = wsB + wsBase + (q1) * 2048 + call_ * 512 + w * 64 + l; \
      char* d_ = ldsB + (nb) * 32768 + call_ * 8192 + w * 1024;          \
      __builtin_amdgcn_global_load_lds((const uint32_t*)g_, (uint32_t*)d_, 16, 0, 0); \
    }                                                                    \
  } while (0)

__global__ __launch_bounds__(512) void gcn_kernel(
    const float* __restrict__ adj, const u32x4* __restrict__ wsB,
    float* __restrict__ out) {
  __shared__ char ldsB[65536];  // 2 x 32 KB bf16 B-phase buffers

  const int tid = (int)threadIdx.x;
  const int l = tid & 63;
  const int w = tid >> 6;  // wave 0..7
  const int bid = (int)blockIdx.x;  // 256 WGs: xcd(3b)|rtile(3b)|bb(2b)
  const int batch = (bid & 7) * 4 + (bid >> 6);
  const int rtile = (bid >> 3) & 7;
  const int rbase = rtile * 128;

  const float* aB = adj + (size_t)batch * 1048576;
  float* oB = out + (size_t)batch * 131072;
  const size_t wsBase = (size_t)batch * 16384;  // 16B chunks

  const int arow = rbase + w * 16 + (l & 15);
  const int kg = (l >> 4) * 8;
  const float* aP = aB + (size_t)arow * 1024 + kg;
  const int diag_kt = arow >> 6;  // wave-uniform (16-row blocks don't straddle 64)

  const char* rP = ldsB + l * 16;

  f32x4 acc[8];
#pragma unroll
  for (int n = 0; n < 8; ++n) { f32x4 z = {0.f, 0.f, 0.f, 0.f}; acc[n] = z; }

  f32x4 Ar[2][4];  // compile-time indexed under full unroll

  // Prologue: stage phase 0 -> buf0; prefetch A(0)
  GLDSPHASE(0, 0);
  LOADA(0, Ar[0]);
  __syncthreads();  // implicit vmcnt(0) drain covers glds

#pragma unroll
  for (int kt = 0; kt < 16; ++kt) {
    const int q = kt >> 1;
    const int c = kt & 1;
    const int buf = q & 1;
    const int nbuf = buf ^ 1;
    const int cur = kt & 1;
    const int nxt = cur ^ 1;

    if (c == 0 && q < 7) GLDSPHASE(nbuf, q + 1);  // in flight across the phase
    if (kt < 15) LOADA(kt + 1, Ar[nxt]);
    COMPUTE(buf, kt, Ar[cur]);
    if (c == 1) __syncthreads();  // publish nbuf; 8 barriers total
  }

  // Epilogue: C/D col = l&15, row = (l>>4)*4 + j (64B-dense segments)
  const int orow = rbase + w * 16 + (l >> 4) * 4;
  const int ocol = l & 15;
  float* op = oB + (size_t)orow * 128 + ocol;
#pragma unroll
  for (int n = 0; n < 8; ++n)
#pragma unroll
    for (int j = 0; j < 4; ++j)
      op[j * 128 + n * 16] = acc[n][j];
}

extern "C" void kernel_launch(void* const* d_in, const int* in_sizes, int n_in,
                              void* d_out, int out_size, void* d_ws, size_t ws_size,
                              hipStream_t stream) {
  const float* means = (const float*)d_in[0];  // regional_means (32,1024,128)
  const float* adj = (const float*)d_in[1];    // adj (32,1024,1024)
  float* out = (float*)d_out;                  // (32,1024,128) f32
  u32x4* wsB = (u32x4*)d_ws;                   // 8 MB bf16 fragment-ordered B

  hipLaunchKernelGGL(conv_means, dim3(2048), dim3(256), 0, stream, means, wsB);
  hipLaunchKernelGGL(gcn_kernel, dim3(256), dim3(512), 0, stream,
                     adj, (const u32x4*)wsB, out);
}